// Round 1
// baseline (588.141 us; speedup 1.0000x reference)
//
#include <hip/hip_runtime.h>

#define BB 8
#define CC 256
#define DD 128
#define NN 4096
#define BN_EPS 1e-5f

typedef _Float16 f16;
typedef _Float16 half8 __attribute__((ext_vector_type(8)));
typedef float f32x4 __attribute__((ext_vector_type(4)));

__device__ __forceinline__ f32x4 mfma16(half8 a, half8 b, f32x4 c) {
  return __builtin_amdgcn_mfma_f32_16x16x32_f16(a, b, c, 0, 0, 0);
}

// ---------- weights cast (fp32 -> fp16), stats zero ----------
__global__ void k_cast_weights(const float* __restrict__ tw, const float* __restrict__ pw,
                               const float* __restrict__ gw, const float* __restrict__ ww,
                               f16* __restrict__ Wcat, f16* __restrict__ Wwh,
                               float* __restrict__ stats) {
  int i = blockIdx.x * 256 + threadIdx.x;
  if (i < 32768) Wcat[i] = (f16)tw[i];                       // rows 0..127: theta_w
  else if (i < 65536) Wcat[i] = (f16)pw[i - 32768];          // rows 128..255: phi_w
  else if (i < 98304) Wcat[i] = (f16)gw[i - 65536];          // rows 256..383: g_w
  else if (i < 131072) Wwh[i - 98304] = (f16)ww[i - 98304];  // [C][D]
  if (i < 512) stats[i] = 0.f;
}

// ---------- x [B][C][N] f32 -> xT [B][N][C] f16 ----------
__global__ void k_transpose_x(const float* __restrict__ x, f16* __restrict__ xT) {
  __shared__ f16 tile[32][33];
  int b = blockIdx.z, c0 = blockIdx.y * 32, n0 = blockIdx.x * 32;
  int tx = threadIdx.x, ty = threadIdx.y;
  const float* xp = x + ((size_t)b * CC + c0) * NN + n0;
  for (int j = 0; j < 4; ++j) {
    int cc = ty + j * 8;
    tile[cc][tx] = (f16)xp[(size_t)cc * NN + tx];
  }
  __syncthreads();
  f16* xo = xT + ((size_t)b * NN + n0) * CC + c0;
  for (int j = 0; j < 4; ++j) {
    int nn = ty + j * 8;
    xo[(size_t)nn * CC + tx] = tile[tx][nn];
  }
}

// ---------- projections: C1[n][m] = sum_c xT[n][c] * Wcat[m][c] ----------
// split columns: m<128 -> T[n][m], m<256 -> P[n][m-128], else Gnd[n][m-256]
__global__ __launch_bounds__(256) void k_gemm1(const f16* __restrict__ xT, const f16* __restrict__ Wcat,
                                               f16* __restrict__ T, f16* __restrict__ P,
                                               f16* __restrict__ Gnd) {
  int b = blockIdx.z;
  int lane = threadIdx.x & 63, wave = threadIdx.x >> 6;
  int lr = lane & 15, lg = lane >> 4;
  int wr = wave >> 1, wc = wave & 1;
  int m0 = blockIdx.x * 64 + wr * 32;  // position n
  int c0 = blockIdx.y * 64 + wc * 32;  // out channel
  const f16* A = xT + (size_t)b * NN * CC;
  f32x4 acc[2][2] = {};
  for (int k0 = 0; k0 < CC; k0 += 32) {
    half8 a[2], w[2];
    for (int i = 0; i < 2; ++i)
      a[i] = *(const half8*)(A + (size_t)(m0 + i * 16 + lr) * CC + k0 + lg * 8);
    for (int j = 0; j < 2; ++j)
      w[j] = *(const half8*)(Wcat + (size_t)(c0 + j * 16 + lr) * CC + k0 + lg * 8);
    for (int i = 0; i < 2; ++i)
      for (int j = 0; j < 2; ++j)
        acc[i][j] = mfma16(a[i], w[j], acc[i][j]);
  }
  for (int i = 0; i < 2; ++i)
    for (int j = 0; j < 2; ++j)
      for (int r = 0; r < 4; ++r) {
        int row = m0 + i * 16 + lg * 4 + r;
        int col = c0 + j * 16 + lr;
        f16 v = (f16)acc[i][j][r];
        size_t base = (size_t)b * NN + row;
        if (col < DD) T[base * DD + col] = v;
        else if (col < 2 * DD) P[base * DD + col - DD] = v;
        else Gnd[base * DD + col - 2 * DD] = v;
      }
}

// ---------- Gnd [B][N][D] -> Gdn [B][D][N] (V^T layout) ----------
__global__ void k_transpose_g(const f16* __restrict__ Gnd, f16* __restrict__ Gdn) {
  __shared__ f16 tile[32][33];
  int b = blockIdx.z, d0 = blockIdx.y * 32, n0 = blockIdx.x * 32;
  int tx = threadIdx.x, ty = threadIdx.y;
  for (int j = 0; j < 4; ++j) {
    int nn = ty + j * 8;
    tile[nn][tx] = Gnd[((size_t)b * NN + n0 + nn) * DD + d0 + tx];
  }
  __syncthreads();
  for (int j = 0; j < 4; ++j) {
    int dd = ty + j * 8;
    Gdn[((size_t)b * DD + d0 + dd) * NN + n0 + tx] = tile[tx][dd];
  }
}

// ---------- flash attention: Y[n][d] = softmax(T P^T)[n][:] @ Gnd ----------
// 4 waves/block, each wave = 16 query rows; KV block = 64
__global__ __launch_bounds__(256) void k_flash(const f16* __restrict__ T, const f16* __restrict__ P,
                                               const f16* __restrict__ Gdn, f16* __restrict__ Y) {
  __shared__ f16 Plds[4][16][72];  // per-wave P tile, stride 72 halves = 144B (16B-aligned rows)
  int b = blockIdx.y;
  int lane = threadIdx.x & 63, wave = threadIdx.x >> 6;
  int lr = lane & 15, lg = lane >> 4;
  int q0 = blockIdx.x * 64 + wave * 16;
  const f16* Tb = T + (size_t)b * NN * DD;
  const f16* Pb = P + (size_t)b * NN * DD;
  const f16* Vb = Gdn + (size_t)b * DD * NN;
  half8 qf[4];
  for (int ks = 0; ks < 4; ++ks)
    qf[ks] = *(const half8*)(Tb + (size_t)(q0 + lr) * DD + ks * 32 + lg * 8);
  f32x4 acc[8] = {};
  float m_run[4], l_run[4];
  for (int r = 0; r < 4; ++r) { m_run[r] = -1e30f; l_run[r] = 0.f; }

  for (int kb = 0; kb < NN / 64; ++kb) {
    int key0 = kb * 64;
    // scores S[16q][64k]
    f32x4 s[4];
    for (int kt = 0; kt < 4; ++kt) {
      f32x4 t = {};
      for (int ks = 0; ks < 4; ++ks) {
        half8 kf = *(const half8*)(Pb + (size_t)(key0 + kt * 16 + lr) * DD + ks * 32 + lg * 8);
        t = mfma16(qf[ks], kf, t);
      }
      s[kt] = t;
    }
    // online softmax (row = lg*4+r, col = lane&15 within each kt tile)
    float corr[4];
    for (int r = 0; r < 4; ++r) {
      float mx = fmaxf(fmaxf(s[0][r], s[1][r]), fmaxf(s[2][r], s[3][r]));
      for (int off = 1; off < 16; off <<= 1) mx = fmaxf(mx, __shfl_xor(mx, off));
      float mn = fmaxf(m_run[r], mx);
      corr[r] = __expf(m_run[r] - mn);
      float rs = 0.f;
      for (int kt = 0; kt < 4; ++kt) {
        float p = __expf(s[kt][r] - mn);
        s[kt][r] = p;
        rs += p;
      }
      for (int off = 1; off < 16; off <<= 1) rs += __shfl_xor(rs, off);
      l_run[r] = l_run[r] * corr[r] + rs;
      m_run[r] = mn;
    }
    for (int nb = 0; nb < 8; ++nb)
      for (int r = 0; r < 4; ++r) acc[nb][r] *= corr[r];
    // P (C-layout) -> LDS -> A-fragment layout
    for (int kt = 0; kt < 4; ++kt)
      for (int r = 0; r < 4; ++r)
        Plds[wave][lg * 4 + r][kt * 16 + lr] = (f16)s[kt][r];
    asm volatile("s_waitcnt lgkmcnt(0)" ::: "memory");
    __builtin_amdgcn_sched_barrier(0);
    half8 af[2];
    for (int kst = 0; kst < 2; ++kst)
      af[kst] = *(const half8*)(&Plds[wave][lr][kst * 32 + lg * 8]);
    // PV: acc[nb] += P[16][64] @ V[64][d-tile]
    for (int nb = 0; nb < 8; ++nb)
      for (int kst = 0; kst < 2; ++kst) {
        half8 vf = *(const half8*)(Vb + (size_t)(nb * 16 + lr) * NN + key0 + kst * 32 + lg * 8);
        acc[nb] = mfma16(af[kst], vf, acc[nb]);
      }
  }
  float inv_l[4];
  for (int r = 0; r < 4; ++r) inv_l[r] = 1.f / l_run[r];
  f16* Yb = Y + (size_t)b * NN * DD;
  for (int nb = 0; nb < 8; ++nb)
    for (int r = 0; r < 4; ++r)
      Yb[(size_t)(q0 + lg * 4 + r) * DD + nb * 16 + lr] = (f16)(acc[nb][r] * inv_l[r]);
}

// ---------- output projection: wy[row][c] = sum_d Y[row][d]*Ww[c][d] + wb[c] ----------
__global__ __launch_bounds__(256) void k_gemm2(const f16* __restrict__ Y, const f16* __restrict__ Wwh,
                                               const float* __restrict__ wb, float* __restrict__ wy) {
  int lane = threadIdx.x & 63, wave = threadIdx.x >> 6;
  int lr = lane & 15, lg = lane >> 4;
  int wr = wave >> 1, wc = wave & 1;
  int m0 = blockIdx.x * 64 + wr * 32;  // row over B*N
  int c0 = blockIdx.y * 64 + wc * 32;
  f32x4 acc[2][2] = {};
  for (int k0 = 0; k0 < DD; k0 += 32) {
    half8 a[2], w[2];
    for (int i = 0; i < 2; ++i)
      a[i] = *(const half8*)(Y + (size_t)(m0 + i * 16 + lr) * DD + k0 + lg * 8);
    for (int j = 0; j < 2; ++j)
      w[j] = *(const half8*)(Wwh + (size_t)(c0 + j * 16 + lr) * DD + k0 + lg * 8);
    for (int i = 0; i < 2; ++i)
      for (int j = 0; j < 2; ++j)
        acc[i][j] = mfma16(a[i], w[j], acc[i][j]);
  }
  for (int i = 0; i < 2; ++i)
    for (int j = 0; j < 2; ++j)
      for (int r = 0; r < 4; ++r) {
        int row = m0 + i * 16 + lg * 4 + r;
        int col = c0 + j * 16 + lr;
        wy[(size_t)row * CC + col] = acc[i][j][r] + wb[col];
      }
}

// ---------- BN stats: per-channel sum & sumsq over (b,n) ----------
__global__ void k_bn_stats(const float* __restrict__ wy, float* __restrict__ stats) {
  int c = threadIdx.x;
  int rows = (BB * NN) / gridDim.x;
  int base = blockIdx.x * rows;
  float s = 0.f, ss = 0.f;
  for (int i = 0; i < rows; ++i) {
    float v = wy[(size_t)(base + i) * CC + c];
    s += v;
    ss += v * v;
  }
  atomicAdd(&stats[c], s);
  atomicAdd(&stats[CC + c], ss);
}

// ---------- BN apply + residual, [B][N][C] -> [B][C][N] via LDS transpose ----------
__global__ void k_bn_apply(const float* __restrict__ wy, const float* __restrict__ x,
                           const float* __restrict__ stats, const float* __restrict__ gamma,
                           const float* __restrict__ beta, float* __restrict__ out) {
  __shared__ float tile[32][33];
  int b = blockIdx.z, c0 = blockIdx.y * 32, n0 = blockIdx.x * 32;
  int tx = threadIdx.x, ty = threadIdx.y;
  for (int j = 0; j < 4; ++j) {
    int nn = ty + j * 8;
    tile[nn][tx] = wy[((size_t)b * NN + n0 + nn) * CC + c0 + tx];
  }
  __syncthreads();
  const float inv_cnt = 1.f / (float)(BB * NN);
  for (int j = 0; j < 4; ++j) {
    int cc = ty + j * 8;
    int c = c0 + cc;
    float mean = stats[c] * inv_cnt;
    float var = stats[CC + c] * inv_cnt - mean * mean;
    float scale = gamma[c] * rsqrtf(var + BN_EPS);
    size_t oi = ((size_t)b * CC + c) * NN + n0 + tx;
    out[oi] = (tile[tx][cc] - mean) * scale + beta[c] + x[oi];
  }
}

extern "C" void kernel_launch(void* const* d_in, const int* in_sizes, int n_in,
                              void* d_out, int out_size, void* d_ws, size_t ws_size,
                              hipStream_t stream) {
  const float* x = (const float*)d_in[0];
  const float* tw = (const float*)d_in[1];
  const float* pw = (const float*)d_in[2];
  const float* gw = (const float*)d_in[3];
  const float* ww = (const float*)d_in[4];
  const float* wb = (const float*)d_in[5];
  const float* gamma = (const float*)d_in[6];
  const float* beta = (const float*)d_in[7];
  float* out = (float*)d_out;
  char* ws = (char*)d_ws;

  // workspace layout (65 MB total):
  f16* Wcat = (f16*)(ws + 0);                 // 384*256*2
  f16* Wwh = (f16*)(ws + 196608);             // 256*128*2
  float* stats = (float*)(ws + 262144);       // 512*4
  const size_t BASE = 1 << 20;
  f16* T = (f16*)(ws + BASE);                           // 8 MB  [B][N][D]
  f16* P = (f16*)(ws + BASE + 8388608);                 // 8 MB  [B][N][D]
  f16* Gdn = (f16*)(ws + BASE + 16777216);              // 8 MB  [B][D][N]
  f16* Y = (f16*)(ws + BASE + 25165824);                // 8 MB  [B][N][D]
  f16* xT = (f16*)(ws + BASE + 33554432);               // 16 MB [B][N][C]  (dead after gemm1)
  f16* Gnd = (f16*)(ws + BASE + 33554432 + 16777216);   // 8 MB  [B][N][D]  (dead after transpose_g)
  float* wy = (float*)(ws + BASE + 33554432);           // 32 MB [B][N][C]  fp32 (reuses xT+Gnd region)

  k_cast_weights<<<512, 256, 0, stream>>>(tw, pw, gw, ww, Wcat, Wwh, stats);
  k_transpose_x<<<dim3(NN / 32, CC / 32, BB), dim3(32, 8), 0, stream>>>(x, xT);
  k_gemm1<<<dim3(NN / 64, 384 / 64, BB), 256, 0, stream>>>(xT, Wcat, T, P, Gnd);
  k_transpose_g<<<dim3(NN / 32, DD / 32, BB), dim3(32, 8), 0, stream>>>(Gnd, Gdn);
  k_flash<<<dim3(NN / 64, BB), 256, 0, stream>>>(T, P, Gdn, Y);
  k_gemm2<<<dim3(BB * NN / 64, CC / 64), 256, 0, stream>>>(Y, Wwh, wb, wy);
  k_bn_stats<<<256, 256, 0, stream>>>(wy, stats);
  k_bn_apply<<<dim3(NN / 32, CC / 32, BB), dim3(32, 8), 0, stream>>>(wy, x, stats, gamma, beta, out);
}

// Round 2
// 305.013 us; speedup vs baseline: 1.9282x; 1.9282x over previous
//
#include <hip/hip_runtime.h>

#define BB 8
#define CC 256
#define DD 128
#define NN 4096
#define BN_EPS 1e-5f

typedef _Float16 f16;
typedef _Float16 half8 __attribute__((ext_vector_type(8)));
typedef float f32x4 __attribute__((ext_vector_type(4)));

__device__ __forceinline__ f32x4 mfma16(half8 a, half8 b, f32x4 c) {
  return __builtin_amdgcn_mfma_f32_16x16x32_f16(a, b, c, 0, 0, 0);
}

__device__ __forceinline__ void gload_lds16(const void* g, void* l) {
  __builtin_amdgcn_global_load_lds((const __attribute__((address_space(1))) void*)g,
                                   (__attribute__((address_space(3))) void*)l, 16, 0, 0);
}

// ---------- weights cast (fp32 -> fp16), stats zero ----------
__global__ void k_cast_weights(const float* __restrict__ tw, const float* __restrict__ pw,
                               const float* __restrict__ gw, const float* __restrict__ ww,
                               f16* __restrict__ Wcat, f16* __restrict__ Wwh,
                               float* __restrict__ stats) {
  int i = blockIdx.x * 256 + threadIdx.x;
  if (i < 32768) Wcat[i] = (f16)tw[i];
  else if (i < 65536) Wcat[i] = (f16)pw[i - 32768];
  else if (i < 98304) Wcat[i] = (f16)gw[i - 65536];
  else if (i < 131072) Wwh[i - 98304] = (f16)ww[i - 98304];
  if (i < 512) stats[i] = 0.f;
}

// ---------- x [B][C][N] f32 -> xT [B][N][C] f16 ----------
__global__ void k_transpose_x(const float* __restrict__ x, f16* __restrict__ xT) {
  __shared__ f16 tile[32][33];
  int b = blockIdx.z, c0 = blockIdx.y * 32, n0 = blockIdx.x * 32;
  int tx = threadIdx.x, ty = threadIdx.y;
  const float* xp = x + ((size_t)b * CC + c0) * NN + n0;
  for (int j = 0; j < 4; ++j) {
    int cc = ty + j * 8;
    tile[cc][tx] = (f16)xp[(size_t)cc * NN + tx];
  }
  __syncthreads();
  f16* xo = xT + ((size_t)b * NN + n0) * CC + c0;
  for (int j = 0; j < 4; ++j) {
    int nn = ty + j * 8;
    xo[(size_t)nn * CC + tx] = tile[tx][nn];
  }
}

// ---------- projections ----------
__global__ __launch_bounds__(256) void k_gemm1(const f16* __restrict__ xT, const f16* __restrict__ Wcat,
                                               f16* __restrict__ T, f16* __restrict__ P,
                                               f16* __restrict__ Gnd) {
  int b = blockIdx.z;
  int lane = threadIdx.x & 63, wave = threadIdx.x >> 6;
  int lr = lane & 15, lg = lane >> 4;
  int wr = wave >> 1, wc = wave & 1;
  int m0 = blockIdx.x * 64 + wr * 32;
  int c0 = blockIdx.y * 64 + wc * 32;
  const f16* A = xT + (size_t)b * NN * CC;
  f32x4 acc[2][2] = {};
  for (int k0 = 0; k0 < CC; k0 += 32) {
    half8 a[2], w[2];
    for (int i = 0; i < 2; ++i)
      a[i] = *(const half8*)(A + (size_t)(m0 + i * 16 + lr) * CC + k0 + lg * 8);
    for (int j = 0; j < 2; ++j)
      w[j] = *(const half8*)(Wcat + (size_t)(c0 + j * 16 + lr) * CC + k0 + lg * 8);
    for (int i = 0; i < 2; ++i)
      for (int j = 0; j < 2; ++j)
        acc[i][j] = mfma16(a[i], w[j], acc[i][j]);
  }
  for (int i = 0; i < 2; ++i)
    for (int j = 0; j < 2; ++j)
      for (int r = 0; r < 4; ++r) {
        int row = m0 + i * 16 + lg * 4 + r;
        int col = c0 + j * 16 + lr;
        f16 v = (f16)acc[i][j][r];
        size_t base = (size_t)b * NN + row;
        if (col < DD) T[base * DD + col] = v;
        else if (col < 2 * DD) P[base * DD + col - DD] = v;
        else Gnd[base * DD + col - 2 * DD] = v;
      }
}

// ---------- Gnd [B][N][D] -> Gdn [B][D][N] ----------
__global__ void k_transpose_g(const f16* __restrict__ Gnd, f16* __restrict__ Gdn) {
  __shared__ f16 tile[32][33];
  int b = blockIdx.z, d0 = blockIdx.y * 32, n0 = blockIdx.x * 32;
  int tx = threadIdx.x, ty = threadIdx.y;
  for (int j = 0; j < 4; ++j) {
    int nn = ty + j * 8;
    tile[nn][tx] = Gnd[((size_t)b * NN + n0 + nn) * DD + d0 + tx];
  }
  __syncthreads();
  for (int j = 0; j < 4; ++j) {
    int dd = ty + j * 8;
    Gdn[((size_t)b * DD + d0 + dd) * NN + n0 + tx] = tile[tx][dd];
  }
}

// ---------- flash attention with LDS-staged K/V ----------
// 4 waves/block, each wave 16 q rows; KV block 64.
// LDS: K double-buffered 2x16KB (swizzled), V 16KB (swizzled), P 4x16x72 f16.
__global__ __launch_bounds__(256) void k_flash(const f16* __restrict__ T, const f16* __restrict__ P,
                                               const f16* __restrict__ Gdn, f16* __restrict__ Y) {
  __shared__ char smem[58624];
  f16(*Plds)[16][72] = (f16(*)[16][72])(smem + 49152);
  char* Vbuf = smem + 32768;
  int bid = blockIdx.x;
  int b = bid & 7;   // batch -> XCD pinning (bid % 8 round-robins XCDs)
  int qx = bid >> 3;
  int tid = threadIdx.x;
  int lane = tid & 63, wave = tid >> 6;
  int lr = lane & 15, lg = lane >> 4;
  int q0 = qx * 64 + wave * 16;
  const f16* Tb = T + (size_t)b * NN * DD;
  const f16* Pb = P + (size_t)b * NN * DD;
  const f16* Vb = Gdn + (size_t)b * DD * NN;

  half8 qf[4];
  for (int ks = 0; ks < 4; ++ks)
    qf[ks] = *(const half8*)(Tb + (size_t)(q0 + lr) * DD + ks * 32 + lg * 8);
  f32x4 acc[8] = {};
  float m_run[4], l_run[4];
  for (int r = 0; r < 4; ++r) { m_run[r] = -1e30f; l_run[r] = 0.f; }

  // prologue: stage K tile 0 into buf0 (inverse-swizzled source, linear dest)
  for (int inst = 0; inst < 4; ++inst) {
    int t = inst * 256 + tid;
    int row = t >> 4, sp = t & 15, sl = sp ^ (row & 7);
    gload_lds16(Pb + (size_t)row * DD + sl * 8, smem + (inst * 256 + wave * 64) * 16);
  }

  for (int kb = 0; kb < 64; ++kb) {
    int key0 = kb * 64;
    char* Kc = (kb & 1) ? smem + 16384 : smem;
    char* Kn = (kb & 1) ? smem : smem + 16384;
    // stage V(kb) (consumed after QK+softmax this iteration)
    for (int inst = 0; inst < 4; ++inst) {
      int t = inst * 256 + tid;
      int row = t >> 3, sp = t & 7, sl = sp ^ (row & 7);
      gload_lds16(Vb + (size_t)row * NN + key0 + sl * 8, Vbuf + (inst * 256 + wave * 64) * 16);
    }
    // prefetch K(kb+1)
    if (kb < 63) {
      for (int inst = 0; inst < 4; ++inst) {
        int t = inst * 256 + tid;
        int row = t >> 4, sp = t & 15, sl = sp ^ (row & 7);
        gload_lds16(Pb + (size_t)(key0 + 64 + row) * DD + sl * 8, Kn + (inst * 256 + wave * 64) * 16);
      }
      asm volatile("s_waitcnt vmcnt(8)" ::: "memory");  // K(kb) done; V(kb)+K(kb+1) in flight
    } else {
      asm volatile("s_waitcnt vmcnt(4)" ::: "memory");  // K(kb) done; V(kb) in flight
    }
    __builtin_amdgcn_sched_barrier(0);
    __builtin_amdgcn_s_barrier();
    __builtin_amdgcn_sched_barrier(0);

    // QK^T from swizzled K LDS
    f32x4 s[4];
    __builtin_amdgcn_s_setprio(1);
    for (int kt = 0; kt < 4; ++kt) {
      f32x4 t = {};
      for (int ks = 0; ks < 4; ++ks) {
        half8 kf = *(const half8*)(Kc + (kt * 16 + lr) * 256 + (((ks * 4 + lg) ^ (lr & 7)) << 4));
        t = mfma16(qf[ks], kf, t);
      }
      s[kt] = t;
    }
    __builtin_amdgcn_s_setprio(0);

    // online softmax
    float corr[4];
    for (int r = 0; r < 4; ++r) {
      float mx = fmaxf(fmaxf(s[0][r], s[1][r]), fmaxf(s[2][r], s[3][r]));
      for (int off = 1; off < 16; off <<= 1) mx = fmaxf(mx, __shfl_xor(mx, off));
      float mn = fmaxf(m_run[r], mx);
      corr[r] = __expf(m_run[r] - mn);
      float rs = 0.f;
      for (int kt = 0; kt < 4; ++kt) {
        float p = __expf(s[kt][r] - mn);
        s[kt][r] = p;
        rs += p;
      }
      for (int off = 1; off < 16; off <<= 1) rs += __shfl_xor(rs, off);
      l_run[r] = l_run[r] * corr[r] + rs;
      m_run[r] = mn;
    }
    for (int nb = 0; nb < 8; ++nb)
      for (int r = 0; r < 4; ++r) acc[nb][r] *= corr[r];

    // P -> LDS -> A-fragment
    for (int kt = 0; kt < 4; ++kt)
      for (int r = 0; r < 4; ++r)
        Plds[wave][lg * 4 + r][kt * 16 + lr] = (f16)s[kt][r];
    asm volatile("s_waitcnt lgkmcnt(0)" ::: "memory");
    __builtin_amdgcn_sched_barrier(0);
    half8 af[2];
    for (int kst = 0; kst < 2; ++kst)
      af[kst] = *(const half8*)(&Plds[wave][lr][kst * 32 + lg * 8]);

    // wait V(kb), sync, then PV
    if (kb < 63) asm volatile("s_waitcnt vmcnt(4)" ::: "memory");
    else asm volatile("s_waitcnt vmcnt(0)" ::: "memory");
    __builtin_amdgcn_sched_barrier(0);
    __builtin_amdgcn_s_barrier();
    __builtin_amdgcn_sched_barrier(0);

    __builtin_amdgcn_s_setprio(1);
    for (int nb = 0; nb < 8; ++nb)
      for (int kst = 0; kst < 2; ++kst) {
        half8 vf = *(const half8*)(Vbuf + (nb * 16 + lr) * 128 + (((kst * 4 + lg) ^ (lr & 7)) << 4));
        acc[nb] = mfma16(af[kst], vf, acc[nb]);
      }
    __builtin_amdgcn_s_setprio(0);
    __builtin_amdgcn_sched_barrier(0);
    __builtin_amdgcn_s_barrier();  // V/P buffers free for next iteration
    __builtin_amdgcn_sched_barrier(0);
  }

  float inv_l[4];
  for (int r = 0; r < 4; ++r) inv_l[r] = 1.f / l_run[r];
  f16* Yb = Y + (size_t)b * NN * DD;
  for (int nb = 0; nb < 8; ++nb)
    for (int r = 0; r < 4; ++r)
      Yb[(size_t)(q0 + lg * 4 + r) * DD + nb * 16 + lr] = (f16)(acc[nb][r] * inv_l[r]);
}

// ---------- output projection ----------
__global__ __launch_bounds__(256) void k_gemm2(const f16* __restrict__ Y, const f16* __restrict__ Wwh,
                                               const float* __restrict__ wb, float* __restrict__ wy) {
  int lane = threadIdx.x & 63, wave = threadIdx.x >> 6;
  int lr = lane & 15, lg = lane >> 4;
  int wr = wave >> 1, wc = wave & 1;
  int m0 = blockIdx.x * 64 + wr * 32;
  int c0 = blockIdx.y * 64 + wc * 32;
  f32x4 acc[2][2] = {};
  for (int k0 = 0; k0 < DD; k0 += 32) {
    half8 a[2], w[2];
    for (int i = 0; i < 2; ++i)
      a[i] = *(const half8*)(Y + (size_t)(m0 + i * 16 + lr) * DD + k0 + lg * 8);
    for (int j = 0; j < 2; ++j)
      w[j] = *(const half8*)(Wwh + (size_t)(c0 + j * 16 + lr) * DD + k0 + lg * 8);
    for (int i = 0; i < 2; ++i)
      for (int j = 0; j < 2; ++j)
        acc[i][j] = mfma16(a[i], w[j], acc[i][j]);
  }
  for (int i = 0; i < 2; ++i)
    for (int j = 0; j < 2; ++j)
      for (int r = 0; r < 4; ++r) {
        int row = m0 + i * 16 + lg * 4 + r;
        int col = c0 + j * 16 + lr;
        wy[(size_t)row * CC + col] = acc[i][j][r] + wb[col];
      }
}

// ---------- BN stats ----------
__global__ void k_bn_stats(const float* __restrict__ wy, float* __restrict__ stats) {
  int c = threadIdx.x;
  int rows = (BB * NN) / gridDim.x;
  int base = blockIdx.x * rows;
  float s = 0.f, ss = 0.f;
  for (int i = 0; i < rows; ++i) {
    float v = wy[(size_t)(base + i) * CC + c];
    s += v;
    ss += v * v;
  }
  atomicAdd(&stats[c], s);
  atomicAdd(&stats[CC + c], ss);
}

// ---------- BN apply + residual ----------
__global__ void k_bn_apply(const float* __restrict__ wy, const float* __restrict__ x,
                           const float* __restrict__ stats, const float* __restrict__ gamma,
                           const float* __restrict__ beta, float* __restrict__ out) {
  __shared__ float tile[32][33];
  int b = blockIdx.z, c0 = blockIdx.y * 32, n0 = blockIdx.x * 32;
  int tx = threadIdx.x, ty = threadIdx.y;
  for (int j = 0; j < 4; ++j) {
    int nn = ty + j * 8;
    tile[nn][tx] = wy[((size_t)b * NN + n0 + nn) * CC + c0 + tx];
  }
  __syncthreads();
  const float inv_cnt = 1.f / (float)(BB * NN);
  for (int j = 0; j < 4; ++j) {
    int cc = ty + j * 8;
    int c = c0 + cc;
    float mean = stats[c] * inv_cnt;
    float var = stats[CC + c] * inv_cnt - mean * mean;
    float scale = gamma[c] * rsqrtf(var + BN_EPS);
    size_t oi = ((size_t)b * CC + c) * NN + n0 + tx;
    out[oi] = (tile[tx][cc] - mean) * scale + beta[c] + x[oi];
  }
}

extern "C" void kernel_launch(void* const* d_in, const int* in_sizes, int n_in,
                              void* d_out, int out_size, void* d_ws, size_t ws_size,
                              hipStream_t stream) {
  const float* x = (const float*)d_in[0];
  const float* tw = (const float*)d_in[1];
  const float* pw = (const float*)d_in[2];
  const float* gw = (const float*)d_in[3];
  const float* ww = (const float*)d_in[4];
  const float* wb = (const float*)d_in[5];
  const float* gamma = (const float*)d_in[6];
  const float* beta = (const float*)d_in[7];
  float* out = (float*)d_out;
  char* ws = (char*)d_ws;

  f16* Wcat = (f16*)(ws + 0);
  f16* Wwh = (f16*)(ws + 196608);
  float* stats = (float*)(ws + 262144);
  const size_t BASE = 1 << 20;
  f16* T = (f16*)(ws + BASE);
  f16* P = (f16*)(ws + BASE + 8388608);
  f16* Gdn = (f16*)(ws + BASE + 16777216);
  f16* Y = (f16*)(ws + BASE + 25165824);
  f16* xT = (f16*)(ws + BASE + 33554432);
  f16* Gnd = (f16*)(ws + BASE + 33554432 + 16777216);
  float* wy = (float*)(ws + BASE + 33554432);

  k_cast_weights<<<512, 256, 0, stream>>>(tw, pw, gw, ww, Wcat, Wwh, stats);
  k_transpose_x<<<dim3(NN / 32, CC / 32, BB), dim3(32, 8), 0, stream>>>(x, xT);
  k_gemm1<<<dim3(NN / 64, 384 / 64, BB), 256, 0, stream>>>(xT, Wcat, T, P, Gnd);
  k_transpose_g<<<dim3(NN / 32, DD / 32, BB), dim3(32, 8), 0, stream>>>(Gnd, Gdn);
  k_flash<<<512, 256, 0, stream>>>(T, P, Gdn, Y);
  k_gemm2<<<dim3(BB * NN / 64, CC / 64), 256, 0, stream>>>(Y, Wwh, wb, wy);
  k_bn_stats<<<256, 256, 0, stream>>>(wy, stats);
  k_bn_apply<<<dim3(NN / 32, CC / 32, BB), dim3(32, 8), 0, stream>>>(wy, x, stats, gamma, beta, out);
}

// Round 4
// 232.806 us; speedup vs baseline: 2.5263x; 1.3102x over previous
//
#include <hip/hip_runtime.h>

#define BB 8
#define CC 256
#define DD 128
#define NN 4096
#define BN_EPS 1e-5f

typedef _Float16 f16;
typedef _Float16 half8 __attribute__((ext_vector_type(8)));
typedef float f32x4 __attribute__((ext_vector_type(4)));

__device__ __forceinline__ f32x4 mfma16(half8 a, half8 b, f32x4 c) {
  return __builtin_amdgcn_mfma_f32_16x16x32_f16(a, b, c, 0, 0, 0);
}

__device__ __forceinline__ void gload_lds16(const void* g, void* l) {
  __builtin_amdgcn_global_load_lds((const __attribute__((address_space(1))) void*)g,
                                   (__attribute__((address_space(3))) void*)l, 16, 0, 0);
}

// 16-lane butterfly reduce via DPP (VALU-speed; avoids ds_swizzle chains).
// steps: quad_perm[1,0,3,2]=0xB1, quad_perm[2,3,0,1]=0x4E, row_half_mirror=0x141, row_mirror=0x140
template <int CTRL>
__device__ __forceinline__ float dpp_mv(float x) {
  int v = __builtin_bit_cast(int, x);
  return __builtin_bit_cast(float, __builtin_amdgcn_update_dpp(0, v, CTRL, 0xF, 0xF, true));
}
__device__ __forceinline__ float dpp_add16(float x) {
  x += dpp_mv<0xB1>(x);
  x += dpp_mv<0x4E>(x);
  x += dpp_mv<0x141>(x);
  x += dpp_mv<0x140>(x);
  return x;
}
__device__ __forceinline__ float dpp_max16(float x) {
  x = fmaxf(x, dpp_mv<0xB1>(x));
  x = fmaxf(x, dpp_mv<0x4E>(x));
  x = fmaxf(x, dpp_mv<0x141>(x));
  x = fmaxf(x, dpp_mv<0x140>(x));
  return x;
}

// ---------- weights cast (fp32 -> fp16), stats zero ----------
__global__ void k_cast_weights(const float* __restrict__ tw, const float* __restrict__ pw,
                               const float* __restrict__ gw, const float* __restrict__ ww,
                               f16* __restrict__ Wcat, f16* __restrict__ Wwh,
                               float* __restrict__ stats) {
  int i = blockIdx.x * 256 + threadIdx.x;
  if (i < 32768) Wcat[i] = (f16)tw[i];
  else if (i < 65536) Wcat[i] = (f16)pw[i - 32768];
  else if (i < 98304) Wcat[i] = (f16)gw[i - 65536];
  else if (i < 131072) Wwh[i - 98304] = (f16)ww[i - 98304];
  if (i < 512) stats[i] = 0.f;
}

// ---------- x [B][C][N] f32 -> xT [B][N][C] f16 ----------
__global__ void k_transpose_x(const float* __restrict__ x, f16* __restrict__ xT) {
  __shared__ f16 tile[32][33];
  int b = blockIdx.z, c0 = blockIdx.y * 32, n0 = blockIdx.x * 32;
  int tx = threadIdx.x, ty = threadIdx.y;
  const float* xp = x + ((size_t)b * CC + c0) * NN + n0;
  for (int j = 0; j < 4; ++j) {
    int cc = ty + j * 8;
    tile[cc][tx] = (f16)xp[(size_t)cc * NN + tx];
  }
  __syncthreads();
  f16* xo = xT + ((size_t)b * NN + n0) * CC + c0;
  for (int j = 0; j < 4; ++j) {
    int nn = ty + j * 8;
    xo[(size_t)nn * CC + tx] = tile[tx][nn];
  }
}

// ---------- projections ----------
__global__ __launch_bounds__(256) void k_gemm1(const f16* __restrict__ xT, const f16* __restrict__ Wcat,
                                               f16* __restrict__ T, f16* __restrict__ P,
                                               f16* __restrict__ Gnd) {
  int b = blockIdx.z;
  int lane = threadIdx.x & 63, wave = threadIdx.x >> 6;
  int lr = lane & 15, lg = lane >> 4;
  int wr = wave >> 1, wc = wave & 1;
  int m0 = blockIdx.x * 64 + wr * 32;
  int c0 = blockIdx.y * 64 + wc * 32;
  const f16* A = xT + (size_t)b * NN * CC;
  f32x4 acc[2][2] = {};
  for (int k0 = 0; k0 < CC; k0 += 32) {
    half8 a[2], w[2];
    for (int i = 0; i < 2; ++i)
      a[i] = *(const half8*)(A + (size_t)(m0 + i * 16 + lr) * CC + k0 + lg * 8);
    for (int j = 0; j < 2; ++j)
      w[j] = *(const half8*)(Wcat + (size_t)(c0 + j * 16 + lr) * CC + k0 + lg * 8);
    for (int i = 0; i < 2; ++i)
      for (int j = 0; j < 2; ++j)
        acc[i][j] = mfma16(a[i], w[j], acc[i][j]);
  }
  for (int i = 0; i < 2; ++i)
    for (int j = 0; j < 2; ++j)
      for (int r = 0; r < 4; ++r) {
        int row = m0 + i * 16 + lg * 4 + r;
        int col = c0 + j * 16 + lr;
        f16 v = (f16)acc[i][j][r];
        size_t base = (size_t)b * NN + row;
        if (col < DD) T[base * DD + col] = v;
        else if (col < 2 * DD) P[base * DD + col - DD] = v;
        else Gnd[base * DD + col - 2 * DD] = v;
      }
}

// ---------- Gnd [B][N][D] -> Gdn [B][D][N] ----------
__global__ void k_transpose_g(const f16* __restrict__ Gnd, f16* __restrict__ Gdn) {
  __shared__ f16 tile[32][33];
  int b = blockIdx.z, d0 = blockIdx.y * 32, n0 = blockIdx.x * 32;
  int tx = threadIdx.x, ty = threadIdx.y;
  for (int j = 0; j < 4; ++j) {
    int nn = ty + j * 8;
    tile[nn][tx] = Gnd[((size_t)b * NN + n0 + nn) * DD + d0 + tx];
  }
  __syncthreads();
  for (int j = 0; j < 4; ++j) {
    int dd = ty + j * 8;
    Gdn[((size_t)b * DD + d0 + dd) * NN + n0 + tx] = tile[tx][dd];
  }
}

// ---------- flash attention ----------
// 4 waves/block, each wave 16 q rows; KV block 64.
// LDS: K 2x16KB dbuf + V 2x16KB dbuf (both XOR-swizzled) + P 4x16x72 = 74.75KB -> 2 blocks/CU.
// Sync: 2 barriers/iter, counted vmcnt(8) (never drains below 8 mid-loop).
// Hazard proof: wave A issuing K(kb+1) has passed B2(kb-1) => all waves finished QK(kb-1)
// (K target buf's last reader). Wave A issuing V(kb+1) has passed B1(kb) => all waves
// finished PV(kb-1) (V target buf's last reader).
__global__ __launch_bounds__(256) void k_flash(const f16* __restrict__ T, const f16* __restrict__ P,
                                               const f16* __restrict__ Gdn, f16* __restrict__ Y) {
  __shared__ char smem[74752];
  f16(*Plds)[16][72] = (f16(*)[16][72])(smem + 65536);
  int bid = blockIdx.x;
  int b = bid & 7;  // batch -> XCD pinning
  int qx = bid >> 3;
  int tid = threadIdx.x;
  int lane = tid & 63, wave = tid >> 6;
  int lr = lane & 15, lg = lane >> 4;
  int q0 = qx * 64 + wave * 16;
  const f16* Tb = T + (size_t)b * NN * DD;
  const f16* Pb = P + (size_t)b * NN * DD;
  const f16* Vb = Gdn + (size_t)b * DD * NN;

  half8 qf[4];
  for (int ks = 0; ks < 4; ++ks)
    qf[ks] = *(const half8*)(Tb + (size_t)(q0 + lr) * DD + ks * 32 + lg * 8);
  f32x4 acc[8] = {};
  float m_run[4], l_run[4];
  for (int r = 0; r < 4; ++r) { m_run[r] = -1e30f; l_run[r] = 0.f; }

  // prologue: stage K(0)->Kbuf0, V(0)->Vbuf0
  for (int inst = 0; inst < 4; ++inst) {
    int t = inst * 256 + tid;
    int row = t >> 4, sp = t & 15, sl = sp ^ (row & 7);
    gload_lds16(Pb + (size_t)row * DD + sl * 8, smem + (inst * 256 + wave * 64) * 16);
  }
  for (int inst = 0; inst < 4; ++inst) {
    int t = inst * 256 + tid;
    int row = t >> 3, sp = t & 7, sl = sp ^ (row & 7);
    gload_lds16(Vb + (size_t)row * NN + sl * 8, smem + 32768 + (inst * 256 + wave * 64) * 16);
  }

  for (int kb = 0; kb < 64; ++kb) {
    int key0 = kb * 64;
    int keyn = (kb < 63) ? key0 + 64 : 0;  // clamp (last prefetch harmless)
    char* Kc = smem + (kb & 1) * 16384;
    char* Kn = smem + ((kb + 1) & 1) * 16384;
    char* Vc = smem + 32768 + (kb & 1) * 16384;
    char* Vn = smem + 32768 + ((kb + 1) & 1) * 16384;

    // issue K(kb+1)
    for (int inst = 0; inst < 4; ++inst) {
      int t = inst * 256 + tid;
      int row = t >> 4, sp = t & 15, sl = sp ^ (row & 7);
      gload_lds16(Pb + (size_t)(keyn + row) * DD + sl * 8, Kn + (inst * 256 + wave * 64) * 16);
    }
    asm volatile("s_waitcnt vmcnt(8)" ::: "memory");  // drains K(kb); V(kb)/K(kb+1) in flight
    __builtin_amdgcn_sched_barrier(0);
    __builtin_amdgcn_s_barrier();  // B1: all waves' K(kb) landed
    __builtin_amdgcn_sched_barrier(0);

    // QK^T
    f32x4 s[4];
    __builtin_amdgcn_s_setprio(1);
    for (int kt = 0; kt < 4; ++kt) {
      f32x4 t = {};
      for (int ks = 0; ks < 4; ++ks) {
        half8 kf = *(const half8*)(Kc + (kt * 16 + lr) * 256 + (((ks * 4 + lg) ^ (lr & 7)) << 4));
        t = mfma16(qf[ks], kf, t);
      }
      s[kt] = t;
    }
    __builtin_amdgcn_s_setprio(0);

    // online softmax with defer-max (THR=8)
    float mx[4];
    for (int r = 0; r < 4; ++r) {
      float m = fmaxf(fmaxf(s[0][r], s[1][r]), fmaxf(s[2][r], s[3][r]));
      mx[r] = dpp_max16(m);
    }
    bool grow = false;
    for (int r = 0; r < 4; ++r) grow |= (mx[r] > m_run[r] + 8.f);
    if (__ballot(grow)) {
      for (int r = 0; r < 4; ++r) {
        float mn = fmaxf(m_run[r], mx[r]);
        float corr = __expf(m_run[r] - mn);
        l_run[r] *= corr;
        m_run[r] = mn;
        for (int nb = 0; nb < 8; ++nb) acc[nb][r] *= corr;
      }
    }
    for (int r = 0; r < 4; ++r) {
      float rs = 0.f;
      for (int kt = 0; kt < 4; ++kt) {
        float p = __expf(s[kt][r] - m_run[r]);
        s[kt][r] = p;
        rs += p;
      }
      l_run[r] += dpp_add16(rs);
    }

    // P -> LDS -> A-fragment
    for (int kt = 0; kt < 4; ++kt)
      for (int r = 0; r < 4; ++r)
        Plds[wave][lg * 4 + r][kt * 16 + lr] = (f16)s[kt][r];
    asm volatile("s_waitcnt lgkmcnt(0)" ::: "memory");
    __builtin_amdgcn_sched_barrier(0);
    half8 af[2];
    for (int kst = 0; kst < 2; ++kst)
      af[kst] = *(const half8*)(&Plds[wave][lr][kst * 32 + lg * 8]);

    // issue V(kb+1), drain own V(kb), barrier -> all waves' V(kb) landed
    for (int inst = 0; inst < 4; ++inst) {
      int t = inst * 256 + tid;
      int row = t >> 3, sp = t & 7, sl = sp ^ (row & 7);
      gload_lds16(Vb + (size_t)row * NN + keyn + sl * 8, Vn + (inst * 256 + wave * 64) * 16);
    }
    asm volatile("s_waitcnt vmcnt(8)" ::: "memory");  // drains V(kb); K/V(kb+1) in flight
    __builtin_amdgcn_sched_barrier(0);
    __builtin_amdgcn_s_barrier();  // B2
    __builtin_amdgcn_sched_barrier(0);

    __builtin_amdgcn_s_setprio(1);
    for (int nb = 0; nb < 8; ++nb)
      for (int kst = 0; kst < 2; ++kst) {
        half8 vf = *(const half8*)(Vc + (nb * 16 + lr) * 128 + (((kst * 4 + lg) ^ (lr & 7)) << 4));
        acc[nb] = mfma16(af[kst], vf, acc[nb]);
      }
    __builtin_amdgcn_s_setprio(0);
  }

  float inv_l[4];
  for (int r = 0; r < 4; ++r) inv_l[r] = 1.f / l_run[r];
  f16* Yb = Y + (size_t)b * NN * DD;
  for (int nb = 0; nb < 8; ++nb)
    for (int r = 0; r < 4; ++r)
      Yb[(size_t)(q0 + lg * 4 + r) * DD + nb * 16 + lr] = (f16)(acc[nb][r] * inv_l[r]);
}

// ---------- output projection + fused BN partial stats ----------
// grid (64, 4): each block does 8 row-tiles of 64, accumulating per-channel sum/sumsq,
// one atomicAdd per channel per block at the end (32K atomics total).
__global__ __launch_bounds__(256) void k_gemm2(const f16* __restrict__ Y, const f16* __restrict__ Wwh,
                                               const float* __restrict__ wb, float* __restrict__ wy,
                                               float* __restrict__ stats) {
  __shared__ float part[2][8][64];  // [metric][wr*4+lg][colLocal]
  int lane = threadIdx.x & 63, wave = threadIdx.x >> 6;
  int lr = lane & 15, lg = lane >> 4;
  int wr = wave >> 1, wc = wave & 1;
  int c0 = blockIdx.y * 64 + wc * 32;
  half8 w[4][2];
  for (int k0 = 0; k0 < 4; ++k0)
    for (int j = 0; j < 2; ++j)
      w[k0][j] = *(const half8*)(Wwh + (size_t)(c0 + j * 16 + lr) * DD + k0 * 32 + lg * 8);
  float bias[2];
  for (int j = 0; j < 2; ++j) bias[j] = wb[c0 + j * 16 + lr];
  float ps[2][2] = {};  // [j][sum, sumsq]
  for (int mt = 0; mt < 8; ++mt) {
    int m0 = (blockIdx.x * 8 + mt) * 64 + wr * 32;
    f32x4 acc[2][2] = {};
    for (int k0 = 0; k0 < 4; ++k0) {
      half8 a[2];
      for (int i = 0; i < 2; ++i)
        a[i] = *(const half8*)(Y + (size_t)(m0 + i * 16 + lr) * DD + k0 * 32 + lg * 8);
      for (int i = 0; i < 2; ++i)
        for (int j = 0; j < 2; ++j)
          acc[i][j] = mfma16(a[i], w[k0][j], acc[i][j]);
    }
    for (int i = 0; i < 2; ++i)
      for (int j = 0; j < 2; ++j)
        for (int r = 0; r < 4; ++r) {
          int row = m0 + i * 16 + lg * 4 + r;
          int col = c0 + j * 16 + lr;
          float v = acc[i][j][r] + bias[j];
          wy[(size_t)row * CC + col] = v;
          ps[j][0] += v;
          ps[j][1] += v * v;
        }
  }
  for (int j = 0; j < 2; ++j) {
    int colL = wc * 32 + j * 16 + lr;
    part[0][wr * 4 + lg][colL] = ps[j][0];
    part[1][wr * 4 + lg][colL] = ps[j][1];
  }
  __syncthreads();
  if (threadIdx.x < 128) {
    int metric = threadIdx.x >> 6, col = threadIdx.x & 63;
    float s = 0.f;
    for (int wtr = 0; wtr < 8; ++wtr) s += part[metric][wtr][col];
    atomicAdd(&stats[metric * CC + blockIdx.y * 64 + col], s);
  }
}

// ---------- BN apply + residual ----------
__global__ void k_bn_apply(const float* __restrict__ wy, const float* __restrict__ x,
                           const float* __restrict__ stats, const float* __restrict__ gamma,
                           const float* __restrict__ beta, float* __restrict__ out) {
  __shared__ float tile[32][33];
  int b = blockIdx.z, c0 = blockIdx.y * 32, n0 = blockIdx.x * 32;
  int tx = threadIdx.x, ty = threadIdx.y;
  for (int j = 0; j < 4; ++j) {
    int nn = ty + j * 8;
    tile[nn][tx] = wy[((size_t)b * NN + n0 + nn) * CC + c0 + tx];
  }
  __syncthreads();
  const float inv_cnt = 1.f / (float)(BB * NN);
  for (int j = 0; j < 4; ++j) {
    int cc = ty + j * 8;
    int c = c0 + cc;
    float mean = stats[c] * inv_cnt;
    float var = stats[CC + c] * inv_cnt - mean * mean;
    float scale = gamma[c] * rsqrtf(var + BN_EPS);
    size_t oi = ((size_t)b * CC + c) * NN + n0 + tx;
    out[oi] = (tile[tx][cc] - mean) * scale + beta[c] + x[oi];
  }
}

extern "C" void kernel_launch(void* const* d_in, const int* in_sizes, int n_in,
                              void* d_out, int out_size, void* d_ws, size_t ws_size,
                              hipStream_t stream) {
  const float* x = (const float*)d_in[0];
  const float* tw = (const float*)d_in[1];
  const float* pw = (const float*)d_in[2];
  const float* gw = (const float*)d_in[3];
  const float* ww = (const float*)d_in[4];
  const float* wb = (const float*)d_in[5];
  const float* gamma = (const float*)d_in[6];
  const float* beta = (const float*)d_in[7];
  float* out = (float*)d_out;
  char* ws = (char*)d_ws;

  f16* Wcat = (f16*)(ws + 0);
  f16* Wwh = (f16*)(ws + 196608);
  float* stats = (float*)(ws + 262144);
  const size_t BASE = 1 << 20;
  f16* T = (f16*)(ws + BASE);
  f16* P = (f16*)(ws + BASE + 8388608);
  f16* Gdn = (f16*)(ws + BASE + 16777216);
  f16* Y = (f16*)(ws + BASE + 25165824);
  f16* xT = (f16*)(ws + BASE + 33554432);
  f16* Gnd = (f16*)(ws + BASE + 33554432 + 16777216);
  float* wy = (float*)(ws + BASE + 33554432);

  k_cast_weights<<<512, 256, 0, stream>>>(tw, pw, gw, ww, Wcat, Wwh, stats);
  k_transpose_x<<<dim3(NN / 32, CC / 32, BB), dim3(32, 8), 0, stream>>>(x, xT);
  k_gemm1<<<dim3(NN / 64, 384 / 64, BB), 256, 0, stream>>>(xT, Wcat, T, P, Gnd);
  k_transpose_g<<<dim3(NN / 32, DD / 32, BB), dim3(32, 8), 0, stream>>>(Gnd, Gdn);
  k_flash<<<512, 256, 0, stream>>>(T, P, Gdn, Y);
  k_gemm2<<<dim3(BB * NN / 512, CC / 64), 256, 0, stream>>>(Y, Wwh, wb, wy, stats);
  k_bn_apply<<<dim3(NN / 32, CC / 32, BB), dim3(32, 8), 0, stream>>>(wy, x, stats, gamma, beta, out);
}